// Round 4
// baseline (374.268 us; speedup 1.0000x reference)
//
#include <hip/hip_runtime.h>
#include <stdint.h>
#include <math.h>

#define NTOK 8192
#define DIM  512
#define FDIM 2048
#define NEXP 8
#define RMAX 17408   // 136 * 128 >= 2*NTOK + NEXP*127 alignment pad
#define NMT  136
#define KSPLIT 2

typedef __attribute__((ext_vector_type(8))) __bf16 bf16x8;
typedef __attribute__((ext_vector_type(4))) float  f32x4;

// ---------------- workspace layout (bytes) ----------------
#define OFF_W1T    ((size_t)0)
#define SZ_W1T     ((size_t)NEXP * DIM * FDIM * 2)   // 16 MiB
#define OFF_W2T    (OFF_W1T + SZ_W1T)
#define SZ_W2T     SZ_W1T
#define OFF_H      (OFF_W2T + SZ_W2T)
#define SZ_H       ((size_t)RMAX * FDIM * 2)         // 68 MiB
#define OFF_META   (OFF_H + SZ_H)                    // counts[8] @0, offsets[9] @8, mtile_e[136] @32
#define SZ_META    ((size_t)1024)
#define OFF_XG     (OFF_META + SZ_META)
#define SZ_XG      ((size_t)RMAX * DIM * 2)          // 17 MiB
#define OFF_O      (OFF_XG + SZ_XG)
#define SZ_O       ((size_t)RMAX * DIM * 4)          // 35.6 MiB (fp32 split-K accumulator)
#define OFF_TOKE   (OFF_O + SZ_O)
#define OFF_TOKSLOT (OFF_TOKE + (size_t)NTOK * 8)
#define OFF_TOKG   (OFF_TOKSLOT + (size_t)NTOK * 8)
#define ZERO_START OFF_META
#define ZERO_LEN   (SZ_META + SZ_XG + SZ_O)

__device__ __forceinline__ unsigned short f2bf(float f) {
  union { float f; unsigned int u; } v; v.f = f;
  unsigned int u = v.u;
  return (unsigned short)((u + 0x7fffu + ((u >> 16) & 1u)) >> 16);
}

// async 16B/lane global->LDS; lds base must be wave-uniform, HW adds lane*16
__device__ __forceinline__ void gld16(const unsigned short* g, unsigned short* l) {
  __builtin_amdgcn_global_load_lds(
      (const __attribute__((address_space(1))) void*)g,
      (__attribute__((address_space(3))) void*)l, 16, 0, 0);
}

// ---------------- transpose + bf16 cast: src [B][R][C] f32 -> dst [B][C][R] bf16 ----------------
__global__ void transpose_cast(const float* __restrict__ src, unsigned short* __restrict__ dst,
                               int R, int C) {
  __shared__ float t[32][33];
  const int b = blockIdx.z;
  const int r0 = blockIdx.y * 32, c0 = blockIdx.x * 32;
  const float* s = src + (size_t)b * R * C;
  unsigned short* d = dst + (size_t)b * R * C;
  const int tr = threadIdx.x >> 5, tc = threadIdx.x & 31;  // tr 0..7
  #pragma unroll
  for (int i = 0; i < 4; i++)
    t[tr + i * 8][tc] = s[(size_t)(r0 + tr + i * 8) * C + (c0 + tc)];
  __syncthreads();
  #pragma unroll
  for (int i = 0; i < 4; i++)
    d[(size_t)(c0 + tr + i * 8) * R + (r0 + tc)] = f2bf(t[tc][tr + i * 8]);
}

// ---------------- gating: fp64 logits, top-2, softmax; hierarchical slot counting ----------------
#define GB 128
#define TPB 64   // tokens per block (4 waves x 16)
__global__ __launch_bounds__(256) void gate_kernel(const float* __restrict__ x,
                            const float* __restrict__ Wg,
                            int* __restrict__ counts, int2* __restrict__ tok_e,
                            int2* __restrict__ tok_slot, float2* __restrict__ tok_g) {
  __shared__ int hist[NEXP];
  __shared__ int base[NEXP];
  __shared__ int le[TPB][2];
  __shared__ int ls[TPB][2];
  __shared__ float lg[TPB][2];
  const int wid = threadIdx.x >> 6;
  const int lane = threadIdx.x & 63;
  if (threadIdx.x < NEXP) hist[threadIdx.x] = 0;
  __syncthreads();
  for (int t = 0; t < 16; t++) {
    const int lt = wid * 16 + t;
    const int n = blockIdx.x * TPB + lt;
    double acc[NEXP];
    #pragma unroll
    for (int e = 0; e < NEXP; e++) acc[e] = 0.0;
    #pragma unroll
    for (int i = 0; i < 8; i++) {
      int dd = lane + i * 64;
      double xv = (double)x[(size_t)n * DIM + dd];
      const float* wr = Wg + (size_t)dd * NEXP;
      #pragma unroll
      for (int e = 0; e < NEXP; e++) acc[e] += xv * (double)wr[e];
    }
    #pragma unroll
    for (int s = 32; s > 0; s >>= 1)
      #pragma unroll
      for (int e = 0; e < NEXP; e++) acc[e] += __shfl_xor(acc[e], s, 64);
    if (lane == 0) {
      int i0 = 0;
      #pragma unroll
      for (int e = 1; e < NEXP; e++) if (acc[e] > acc[i0]) i0 = e;
      int i1 = (i0 == 0) ? 1 : 0;
      #pragma unroll
      for (int e = 0; e < NEXP; e++) { if (e == i0 || e == i1) continue; if (acc[e] > acc[i1]) i1 = e; }
      double e1 = exp(acc[i1] - acc[i0]), ssum = 1.0 + e1;
      le[lt][0] = i0; le[lt][1] = i1;
      ls[lt][0] = atomicAdd(&hist[i0], 1);
      ls[lt][1] = atomicAdd(&hist[i1], 1);
      lg[lt][0] = (float)(1.0 / ssum); lg[lt][1] = (float)(e1 / ssum);
    }
  }
  __syncthreads();
  if (threadIdx.x < NEXP)
    base[threadIdx.x] = atomicAdd(&counts[threadIdx.x], hist[threadIdx.x]);
  __syncthreads();
  if (threadIdx.x < TPB) {
    const int lt = threadIdx.x;
    const int n = blockIdx.x * TPB + lt;
    const int i0 = le[lt][0], i1 = le[lt][1];
    tok_e[n] = make_int2(i0, i1);
    tok_slot[n] = make_int2(base[i0] + ls[lt][0], base[i1] + ls[lt][1]);
    tok_g[n] = make_float2(lg[lt][0], lg[lt][1]);
  }
}

// ---------------- 128-aligned segment offsets + per-M-tile expert id ----------------
__global__ void offsets_kernel(const int* __restrict__ counts, int* __restrict__ offsets,
                               int* __restrict__ mtile_e) {
  if (threadIdx.x == 0 && blockIdx.x == 0) {
    int off = 0;
    for (int e = 0; e < NEXP; e++) { offsets[e] = off; off += (counts[e] + 127) & ~127; }
    offsets[NEXP] = off;
    for (int t = 0; t < NMT; t++) {
      int r = t * 128, e = NEXP - 1;
      for (int q = 0; q < NEXP; q++)
        if (r >= offsets[q] && r < offsets[q + 1]) { e = q; break; }
      mtile_e[t] = e;
    }
  }
}

// ---------------- gather routed token rows into contiguous bf16 segments ----------------
__global__ void gather_kernel(const float* __restrict__ x, const int2* __restrict__ tok_e,
                              const int2* __restrict__ tok_slot,
                              const int* __restrict__ offsets, ushort4* __restrict__ xg) {
  const int p = blockIdx.x, n = p >> 1, k = p & 1;
  int2 te = tok_e[n]; int2 ts = tok_slot[n];
  const int e = k ? te.y : te.x;
  const int slot = k ? ts.y : ts.x;
  const int r = offsets[e] + slot;
  const float4* xr = (const float4*)(x + (size_t)n * DIM);
  float4 v = xr[threadIdx.x];
  ushort4 o;
  o.x = f2bf(v.x); o.y = f2bf(v.y); o.z = f2bf(v.z); o.w = f2bf(v.w);
  xg[(size_t)r * (DIM / 4) + threadIdx.x] = o;
}

// ---------------- 128x128xBK32 bf16 MFMA GEMM core, global_load_lds staging ----------------
// LDS K-chunks are XOR-swizzled (chunk' = chunk ^ ((row>>1)&3)) on the global
// source side: staging lane tid fetches global chunk (tid&3)^((tid>>3)&3) so
// the fixed lane*16 LDS slot holds swizzled data; fragment reads then spread
// each 16-lane phase over 16 banksets 2-way (free) instead of 8-way.
template <int K, int LDA, int LDB>
__device__ __forceinline__ void gemm_core(const unsigned short* __restrict__ A,
                                          const unsigned short* __restrict__ B,
                                          int m0, int n0, f32x4 acc[4][4]) {
  __shared__ __align__(16) unsigned short As[128 * 32];
  __shared__ __align__(16) unsigned short Bs[128 * 32];
  const int tid = threadIdx.x;
  const int wid = tid >> 6, lane = tid & 63;
  const int wm = (wid >> 1) * 64, wn = (wid & 1) * 64;
  const int quad = lane >> 4, l16 = lane & 15;
  const int srow = tid >> 2;                                   // 0..63
  const int scol = (((tid & 3) ^ ((tid >> 3) & 3)) << 3);      // swizzled source chunk
  unsigned short* As_w = As + 512 * wid;
  unsigned short* Bs_w = Bs + 512 * wid;
  const int swz = ((quad ^ ((l16 >> 1) & 3)) << 3);            // read-side chunk offset (elems)
  const unsigned short* Ar0 = A + (size_t)(m0 + srow) * LDA + scol;
  const unsigned short* Ar1 = A + (size_t)(m0 + srow + 64) * LDA + scol;
  const unsigned short* Br0 = B + (size_t)(n0 + srow) * LDB + scol;
  const unsigned short* Br1 = B + (size_t)(n0 + srow + 64) * LDB + scol;
  #pragma unroll 1
  for (int kt = 0; kt < K; kt += 32) {
    __syncthreads();                      // prior iteration's LDS reads done
    gld16(Ar0 + kt, As_w);
    gld16(Ar1 + kt, As_w + 64 * 32);
    gld16(Br0 + kt, Bs_w);
    gld16(Br1 + kt, Bs_w + 64 * 32);
    __syncthreads();                      // drains vmcnt before ds_read
    bf16x8 af[4], bfr[4];
    #pragma unroll
    for (int i = 0; i < 4; i++) {
      af[i]  = *(const bf16x8*)(As + (wm + i * 16 + l16) * 32 + swz);
      bfr[i] = *(const bf16x8*)(Bs + (wn + i * 16 + l16) * 32 + swz);
    }
    #pragma unroll
    for (int mi = 0; mi < 4; mi++)
      #pragma unroll
      for (int ni = 0; ni < 4; ni++)
        acc[mi][ni] = __builtin_amdgcn_mfma_f32_16x16x32_bf16(af[mi], bfr[ni], acc[mi][ni], 0, 0, 0);
  }
}

// ---------------- GEMM1: h = relu(xg @ W1[e] + b1[e]) -> bf16 ----------------
__global__ __launch_bounds__(256) void gemm1_kernel(const unsigned short* __restrict__ xg,
    const unsigned short* __restrict__ W1t, const int* __restrict__ mtile_e,
    const float* __restrict__ b1, unsigned short* __restrict__ h) {
  const int bm = blockIdx.x, bn = blockIdx.y;
  const int e = mtile_e[bm];
  f32x4 acc[4][4];
  #pragma unroll
  for (int i = 0; i < 4; i++)
    #pragma unroll
    for (int j = 0; j < 4; j++) acc[i][j] = (f32x4){0.f, 0.f, 0.f, 0.f};
  gemm_core<DIM, DIM, DIM>(xg, W1t + (size_t)e * FDIM * DIM, bm * 128, bn * 128, acc);
  const int tid = threadIdx.x, wid = tid >> 6, lane = tid & 63;
  const int wm = (wid >> 1) * 64, wn = (wid & 1) * 64, quad = lane >> 4, l16 = lane & 15;
  #pragma unroll
  for (int mi = 0; mi < 4; mi++) {
    #pragma unroll
    for (int ni = 0; ni < 4; ni++) {
      const int col = bn * 128 + wn + ni * 16 + l16;
      const float bb = b1[e * FDIM + col];
      #pragma unroll
      for (int r = 0; r < 4; r++) {
        const int row = bm * 128 + wm + mi * 16 + quad * 4 + r;
        float v = acc[mi][ni][r] + bb;
        h[(size_t)row * FDIM + col] = f2bf(v > 0.f ? v : 0.f);
      }
    }
  }
}

// ---------------- GEMM2 (split-K): o[r,c] += h @ W2[e], fp32 atomic partials ----------------
__global__ __launch_bounds__(256) void gemm2_kernel(const unsigned short* __restrict__ h,
    const unsigned short* __restrict__ W2t, const int* __restrict__ mtile_e,
    float* __restrict__ o) {
  const int bm = blockIdx.x, bn = blockIdx.y, ks = blockIdx.z;
  const int e = mtile_e[bm];
  const int k0 = ks * (FDIM / KSPLIT);
  f32x4 acc[4][4];
  #pragma unroll
  for (int i = 0; i < 4; i++)
    #pragma unroll
    for (int j = 0; j < 4; j++) acc[i][j] = (f32x4){0.f, 0.f, 0.f, 0.f};
  gemm_core<FDIM / KSPLIT, FDIM, FDIM>(h + k0, W2t + (size_t)e * DIM * FDIM + k0,
                                       bm * 128, bn * 128, acc);
  const int tid = threadIdx.x, wid = tid >> 6, lane = tid & 63;
  const int wm = (wid >> 1) * 64, wn = (wid & 1) * 64, quad = lane >> 4, l16 = lane & 15;
  #pragma unroll
  for (int mi = 0; mi < 4; mi++) {
    #pragma unroll
    for (int r = 0; r < 4; r++) {
      const int row = bm * 128 + wm + mi * 16 + quad * 4 + r;
      #pragma unroll
      for (int ni = 0; ni < 4; ni++) {
        const int col = bn * 128 + wn + ni * 16 + l16;
        atomicAdd(&o[(size_t)row * DIM + col], acc[mi][ni][r]);
      }
    }
  }
}

// ---------------- combine: out[n] = log(g0*exp(o[r0]+b2[e0]) + g1*exp(o[r1]+b2[e1])) ----------------
__global__ void combine_kernel(const float* __restrict__ o, const int2* __restrict__ tok_e,
                               const int2* __restrict__ tok_slot, const float2* __restrict__ tok_g,
                               const int* __restrict__ offsets, const float* __restrict__ b2,
                               float* __restrict__ out) {
  const int n = blockIdx.x;
  const int c = threadIdx.x * 4;  // 128 threads x float4
  int2 te = tok_e[n]; int2 ts = tok_slot[n]; float2 tg = tok_g[n];
  const int r0 = offsets[te.x] + ts.x;
  const int r1 = offsets[te.y] + ts.y;
  float4 o0 = *(const float4*)(o + (size_t)r0 * DIM + c);
  float4 o1 = *(const float4*)(o + (size_t)r1 * DIM + c);
  float4 c0 = *(const float4*)(b2 + te.x * DIM + c);
  float4 c1 = *(const float4*)(b2 + te.y * DIM + c);
  float4 res;
  #pragma unroll
  for (int j = 0; j < 4; j++) {
    float v = tg.x * expf(((const float*)&o0)[j] + ((const float*)&c0)[j])
            + tg.y * expf(((const float*)&o1)[j] + ((const float*)&c1)[j]);
    v = (v == 0.0f) ? 2.220446049250313e-16f : v;
    ((float*)&res)[j] = logf(v);
  }
  *(float4*)(out + (size_t)n * DIM + c) = res;
}

extern "C" void kernel_launch(void* const* d_in, const int* in_sizes, int n_in,
                              void* d_out, int out_size, void* d_ws, size_t ws_size,
                              hipStream_t stream) {
  const float* x  = (const float*)d_in[0];
  const float* Wg = (const float*)d_in[1];
  const float* W1 = (const float*)d_in[2];
  const float* b1 = (const float*)d_in[3];
  const float* W2 = (const float*)d_in[4];
  const float* b2 = (const float*)d_in[5];
  float* out = (float*)d_out;
  char* ws = (char*)d_ws;

  unsigned short* W1t = (unsigned short*)(ws + OFF_W1T);
  unsigned short* W2t = (unsigned short*)(ws + OFF_W2T);
  unsigned short* h   = (unsigned short*)(ws + OFF_H);
  int* meta    = (int*)(ws + OFF_META);
  int* counts  = meta;
  int* offsets = meta + 8;
  int* mtile_e = meta + 32;
  unsigned short* xg = (unsigned short*)(ws + OFF_XG);
  float* o       = (float*)(ws + OFF_O);
  int2* tok_e    = (int2*)(ws + OFF_TOKE);
  int2* tok_slot = (int2*)(ws + OFF_TOKSLOT);
  float2* tok_g  = (float2*)(ws + OFF_TOKG);

  hipMemsetAsync(ws + ZERO_START, 0, ZERO_LEN, stream);

  transpose_cast<<<dim3(FDIM / 32, DIM / 32, NEXP), 256, 0, stream>>>(W1, W1t, DIM, FDIM);
  transpose_cast<<<dim3(DIM / 32, FDIM / 32, NEXP), 256, 0, stream>>>(W2, W2t, FDIM, DIM);
  gate_kernel<<<GB, 256, 0, stream>>>(x, Wg, counts, tok_e, tok_slot, tok_g);
  offsets_kernel<<<1, 64, 0, stream>>>(counts, offsets, mtile_e);
  gather_kernel<<<NTOK * 2, 128, 0, stream>>>(x, tok_e, tok_slot, offsets, (ushort4*)xg);
  gemm1_kernel<<<dim3(NMT, FDIM / 128), 256, 0, stream>>>(xg, W1t, mtile_e, b1, h);
  gemm2_kernel<<<dim3(NMT, DIM / 128, KSPLIT), 256, 0, stream>>>(h, W2t, mtile_e, o);
  combine_kernel<<<NTOK, 128, 0, stream>>>(o, tok_e, tok_slot, tok_g, offsets, b2, out);
}

// Round 5
// 360.873 us; speedup vs baseline: 1.0371x; 1.0371x over previous
//
#include <hip/hip_runtime.h>
#include <stdint.h>
#include <math.h>

#define NTOK 8192
#define DIM  512
#define FDIM 2048
#define NEXP 8
#define RMAX 17408   // 136 * 128 >= 2*NTOK + NEXP*127 alignment pad
#define NMT  136
#define KSPLIT 2

typedef __attribute__((ext_vector_type(8))) __bf16 bf16x8;
typedef __attribute__((ext_vector_type(4))) float  f32x4;

// ---------------- workspace layout (bytes) ----------------
#define OFF_W1T    ((size_t)0)
#define SZ_W1T     ((size_t)NEXP * DIM * FDIM * 2)   // 16 MiB
#define OFF_W2T    (OFF_W1T + SZ_W1T)
#define SZ_W2T     SZ_W1T
#define OFF_H      (OFF_W2T + SZ_W2T)
#define SZ_H       ((size_t)RMAX * FDIM * 2)         // 68 MiB
#define OFF_META   (OFF_H + SZ_H)                    // counts[8] @0, offsets[9] @8, mtile_e[136] @32
#define SZ_META    ((size_t)1024)
#define OFF_XG     (OFF_META + SZ_META)
#define SZ_XG      ((size_t)RMAX * DIM * 2)          // 17 MiB
#define OFF_O      (OFF_XG + SZ_XG)
#define SZ_O       ((size_t)RMAX * DIM * 4)          // 35.6 MiB (fp32 split-K accumulator)
#define OFF_TOKE   (OFF_O + SZ_O)
#define OFF_TOKSLOT (OFF_TOKE + (size_t)NTOK * 8)
#define OFF_TOKG   (OFF_TOKSLOT + (size_t)NTOK * 8)
#define ZERO_START OFF_META
#define ZERO_LEN   (SZ_META + SZ_XG + SZ_O)

__device__ __forceinline__ unsigned short f2bf(float f) {
  union { float f; unsigned int u; } v; v.f = f;
  unsigned int u = v.u;
  return (unsigned short)((u + 0x7fffu + ((u >> 16) & 1u)) >> 16);
}

// async 16B/lane global->LDS; lds base must be wave-uniform, HW adds lane*16
__device__ __forceinline__ void gld16(const unsigned short* g, unsigned short* l) {
  __builtin_amdgcn_global_load_lds(
      (const __attribute__((address_space(1))) void*)g,
      (__attribute__((address_space(3))) void*)l, 16, 0, 0);
}

// ---------------- transpose + bf16 cast: src [B][R][C] f32 -> dst [B][C][R] bf16 ----------------
__global__ void transpose_cast(const float* __restrict__ src, unsigned short* __restrict__ dst,
                               int R, int C) {
  __shared__ float t[32][33];
  const int b = blockIdx.z;
  const int r0 = blockIdx.y * 32, c0 = blockIdx.x * 32;
  const float* s = src + (size_t)b * R * C;
  unsigned short* d = dst + (size_t)b * R * C;
  const int tr = threadIdx.x >> 5, tc = threadIdx.x & 31;  // tr 0..7
  #pragma unroll
  for (int i = 0; i < 4; i++)
    t[tr + i * 8][tc] = s[(size_t)(r0 + tr + i * 8) * C + (c0 + tc)];
  __syncthreads();
  #pragma unroll
  for (int i = 0; i < 4; i++)
    d[(size_t)(c0 + tr + i * 8) * R + (r0 + tc)] = f2bf(t[tc][tr + i * 8]);
}

// ---------------- gating: fp64 logits, top-2, softmax; hierarchical slot counting ----------------
#define GB 128
#define TPB 64   // tokens per block (4 waves x 16)
__global__ __launch_bounds__(256) void gate_kernel(const float* __restrict__ x,
                            const float* __restrict__ Wg,
                            int* __restrict__ counts, int2* __restrict__ tok_e,
                            int2* __restrict__ tok_slot, float2* __restrict__ tok_g) {
  __shared__ int hist[NEXP];
  __shared__ int base[NEXP];
  __shared__ int le[TPB][2];
  __shared__ int ls[TPB][2];
  __shared__ float lg[TPB][2];
  const int wid = threadIdx.x >> 6;
  const int lane = threadIdx.x & 63;
  if (threadIdx.x < NEXP) hist[threadIdx.x] = 0;
  __syncthreads();
  for (int t = 0; t < 16; t++) {
    const int lt = wid * 16 + t;
    const int n = blockIdx.x * TPB + lt;
    double acc[NEXP];
    #pragma unroll
    for (int e = 0; e < NEXP; e++) acc[e] = 0.0;
    #pragma unroll
    for (int i = 0; i < 8; i++) {
      int dd = lane + i * 64;
      double xv = (double)x[(size_t)n * DIM + dd];
      const float* wr = Wg + (size_t)dd * NEXP;
      #pragma unroll
      for (int e = 0; e < NEXP; e++) acc[e] += xv * (double)wr[e];
    }
    #pragma unroll
    for (int s = 32; s > 0; s >>= 1)
      #pragma unroll
      for (int e = 0; e < NEXP; e++) acc[e] += __shfl_xor(acc[e], s, 64);
    if (lane == 0) {
      int i0 = 0;
      #pragma unroll
      for (int e = 1; e < NEXP; e++) if (acc[e] > acc[i0]) i0 = e;
      int i1 = (i0 == 0) ? 1 : 0;
      #pragma unroll
      for (int e = 0; e < NEXP; e++) { if (e == i0 || e == i1) continue; if (acc[e] > acc[i1]) i1 = e; }
      double e1 = exp(acc[i1] - acc[i0]), ssum = 1.0 + e1;
      le[lt][0] = i0; le[lt][1] = i1;
      ls[lt][0] = atomicAdd(&hist[i0], 1);
      ls[lt][1] = atomicAdd(&hist[i1], 1);
      lg[lt][0] = (float)(1.0 / ssum); lg[lt][1] = (float)(e1 / ssum);
    }
  }
  __syncthreads();
  if (threadIdx.x < NEXP)
    base[threadIdx.x] = atomicAdd(&counts[threadIdx.x], hist[threadIdx.x]);
  __syncthreads();
  if (threadIdx.x < TPB) {
    const int lt = threadIdx.x;
    const int n = blockIdx.x * TPB + lt;
    const int i0 = le[lt][0], i1 = le[lt][1];
    tok_e[n] = make_int2(i0, i1);
    tok_slot[n] = make_int2(base[i0] + ls[lt][0], base[i1] + ls[lt][1]);
    tok_g[n] = make_float2(lg[lt][0], lg[lt][1]);
  }
}

// ---------------- 128-aligned segment offsets + per-M-tile expert id ----------------
__global__ void offsets_kernel(const int* __restrict__ counts, int* __restrict__ offsets,
                               int* __restrict__ mtile_e) {
  if (threadIdx.x == 0 && blockIdx.x == 0) {
    int off = 0;
    for (int e = 0; e < NEXP; e++) { offsets[e] = off; off += (counts[e] + 127) & ~127; }
    offsets[NEXP] = off;
    for (int t = 0; t < NMT; t++) {
      int r = t * 128, e = NEXP - 1;
      for (int q = 0; q < NEXP; q++)
        if (r >= offsets[q] && r < offsets[q + 1]) { e = q; break; }
      mtile_e[t] = e;
    }
  }
}

// ---------------- gather routed token rows into contiguous bf16 segments ----------------
__global__ void gather_kernel(const float* __restrict__ x, const int2* __restrict__ tok_e,
                              const int2* __restrict__ tok_slot,
                              const int* __restrict__ offsets, ushort4* __restrict__ xg) {
  const int p = blockIdx.x, n = p >> 1, k = p & 1;
  int2 te = tok_e[n]; int2 ts = tok_slot[n];
  const int e = k ? te.y : te.x;
  const int slot = k ? ts.y : ts.x;
  const int r = offsets[e] + slot;
  const float4* xr = (const float4*)(x + (size_t)n * DIM);
  float4 v = xr[threadIdx.x];
  ushort4 o;
  o.x = f2bf(v.x); o.y = f2bf(v.y); o.z = f2bf(v.z); o.w = f2bf(v.w);
  xg[(size_t)r * (DIM / 4) + threadIdx.x] = o;
}

// ---------------- 128x128xBK64 bf16 MFMA GEMM core, global_load_lds staging ----------------
// BK=64: 8 gld16 + 32 MFMA per barrier pair (half the vmcnt(0) drains of BK=32).
// LDS [row][chunk] (8 chunks of 8 elems per row); slot [row][c] holds global
// chunk c ^ (row&7). Staging lane tid -> row tid>>3 (+32/pass), fetches global
// chunk (tid&7)^((tid>>3)&7); slot byte offset = 16*tid + 4096*pass, matching
// the HW's wave-uniform-base + lane*16 contract. Read side: global chunk
// g=kk*4+quad for row l16 lives at slot g^(l16&7); row stride 128B wraps the
// 32 banks exactly, so banks depend only on the swizzled chunk -> 2-way (free).
template <int K, int LDA, int LDB>
__device__ __forceinline__ void gemm_core(const unsigned short* __restrict__ A,
                                          const unsigned short* __restrict__ B,
                                          int m0, int n0, f32x4 acc[4][4]) {
  __shared__ __align__(16) unsigned short As[128 * 64];  // 16 KB
  __shared__ __align__(16) unsigned short Bs[128 * 64];  // 16 KB
  const int tid = threadIdx.x;
  const int wid = tid >> 6, lane = tid & 63;
  const int wm = (wid >> 1) * 64, wn = (wid & 1) * 64;
  const int quad = lane >> 4, l16 = lane & 15;
  const int srow = tid >> 3;                        // 0..31
  const int scol = ((tid & 7) ^ (srow & 7)) << 3;   // swizzled source chunk (elems)
  unsigned short* As_w = As + 512 * wid;            // wave-uniform base (16B*64 per wave)
  unsigned short* Bs_w = Bs + 512 * wid;
  const int r7 = (l16 & 7) << 3;                    // read-side swizzle key (elems)
  const unsigned short* Ar = A + (size_t)(m0 + srow) * LDA + scol;
  const unsigned short* Br = B + (size_t)(n0 + srow) * LDB + scol;
  #pragma unroll 1
  for (int kt = 0; kt < K; kt += 64) {
    __syncthreads();                      // prior iteration's LDS reads done
    #pragma unroll
    for (int p = 0; p < 4; p++) {
      gld16(Ar + (size_t)(32 * p) * LDA + kt, As_w + p * 2048);
      gld16(Br + (size_t)(32 * p) * LDB + kt, Bs_w + p * 2048);
    }
    __syncthreads();                      // drains vmcnt before ds_read
    #pragma unroll
    for (int kk = 0; kk < 2; kk++) {
      const int swz = ((kk * 4 + quad) << 3) ^ r7;  // swizzled chunk offset (elems)
      bf16x8 af[4], bfr[4];
      #pragma unroll
      for (int i = 0; i < 4; i++) {
        af[i]  = *(const bf16x8*)(As + (wm + i * 16 + l16) * 64 + swz);
        bfr[i] = *(const bf16x8*)(Bs + (wn + i * 16 + l16) * 64 + swz);
      }
      #pragma unroll
      for (int mi = 0; mi < 4; mi++)
        #pragma unroll
        for (int ni = 0; ni < 4; ni++)
          acc[mi][ni] = __builtin_amdgcn_mfma_f32_16x16x32_bf16(af[mi], bfr[ni], acc[mi][ni], 0, 0, 0);
    }
  }
}

// ---------------- GEMM1: h = relu(xg @ W1[e] + b1[e]) -> bf16 ----------------
__global__ __launch_bounds__(256) void gemm1_kernel(const unsigned short* __restrict__ xg,
    const unsigned short* __restrict__ W1t, const int* __restrict__ mtile_e,
    const float* __restrict__ b1, unsigned short* __restrict__ h) {
  const int bm = blockIdx.x, bn = blockIdx.y;
  const int e = mtile_e[bm];
  f32x4 acc[4][4];
  #pragma unroll
  for (int i = 0; i < 4; i++)
    #pragma unroll
    for (int j = 0; j < 4; j++) acc[i][j] = (f32x4){0.f, 0.f, 0.f, 0.f};
  gemm_core<DIM, DIM, DIM>(xg, W1t + (size_t)e * FDIM * DIM, bm * 128, bn * 128, acc);
  const int tid = threadIdx.x, wid = tid >> 6, lane = tid & 63;
  const int wm = (wid >> 1) * 64, wn = (wid & 1) * 64, quad = lane >> 4, l16 = lane & 15;
  #pragma unroll
  for (int mi = 0; mi < 4; mi++) {
    #pragma unroll
    for (int ni = 0; ni < 4; ni++) {
      const int col = bn * 128 + wn + ni * 16 + l16;
      const float bb = b1[e * FDIM + col];
      #pragma unroll
      for (int r = 0; r < 4; r++) {
        const int row = bm * 128 + wm + mi * 16 + quad * 4 + r;
        float v = acc[mi][ni][r] + bb;
        h[(size_t)row * FDIM + col] = f2bf(v > 0.f ? v : 0.f);
      }
    }
  }
}

// ---------------- GEMM2 (split-K): o[r,c] += h @ W2[e], fp32 atomic partials ----------------
__global__ __launch_bounds__(256) void gemm2_kernel(const unsigned short* __restrict__ h,
    const unsigned short* __restrict__ W2t, const int* __restrict__ mtile_e,
    float* __restrict__ o) {
  const int bm = blockIdx.x, bn = blockIdx.y, ks = blockIdx.z;
  const int e = mtile_e[bm];
  const int k0 = ks * (FDIM / KSPLIT);
  f32x4 acc[4][4];
  #pragma unroll
  for (int i = 0; i < 4; i++)
    #pragma unroll
    for (int j = 0; j < 4; j++) acc[i][j] = (f32x4){0.f, 0.f, 0.f, 0.f};
  gemm_core<FDIM / KSPLIT, FDIM, FDIM>(h + k0, W2t + (size_t)e * DIM * FDIM + k0,
                                       bm * 128, bn * 128, acc);
  const int tid = threadIdx.x, wid = tid >> 6, lane = tid & 63;
  const int wm = (wid >> 1) * 64, wn = (wid & 1) * 64, quad = lane >> 4, l16 = lane & 15;
  #pragma unroll
  for (int mi = 0; mi < 4; mi++) {
    #pragma unroll
    for (int r = 0; r < 4; r++) {
      const int row = bm * 128 + wm + mi * 16 + quad * 4 + r;
      #pragma unroll
      for (int ni = 0; ni < 4; ni++) {
        const int col = bn * 128 + wn + ni * 16 + l16;
        atomicAdd(&o[(size_t)row * DIM + col], acc[mi][ni][r]);
      }
    }
  }
}

// ---------------- combine: out[n] = log(g0*exp(o[r0]+b2[e0]) + g1*exp(o[r1]+b2[e1])) ----------------
__global__ void combine_kernel(const float* __restrict__ o, const int2* __restrict__ tok_e,
                               const int2* __restrict__ tok_slot, const float2* __restrict__ tok_g,
                               const int* __restrict__ offsets, const float* __restrict__ b2,
                               float* __restrict__ out) {
  const int n = blockIdx.x;
  const int c = threadIdx.x * 4;  // 128 threads x float4
  int2 te = tok_e[n]; int2 ts = tok_slot[n]; float2 tg = tok_g[n];
  const int r0 = offsets[te.x] + ts.x;
  const int r1 = offsets[te.y] + ts.y;
  float4 o0 = *(const float4*)(o + (size_t)r0 * DIM + c);
  float4 o1 = *(const float4*)(o + (size_t)r1 * DIM + c);
  float4 c0 = *(const float4*)(b2 + te.x * DIM + c);
  float4 c1 = *(const float4*)(b2 + te.y * DIM + c);
  float4 res;
  #pragma unroll
  for (int j = 0; j < 4; j++) {
    float v = tg.x * expf(((const float*)&o0)[j] + ((const float*)&c0)[j])
            + tg.y * expf(((const float*)&o1)[j] + ((const float*)&c1)[j]);
    v = (v == 0.0f) ? 2.220446049250313e-16f : v;
    ((float*)&res)[j] = logf(v);
  }
  *(float4*)(out + (size_t)n * DIM + c) = res;
}

extern "C" void kernel_launch(void* const* d_in, const int* in_sizes, int n_in,
                              void* d_out, int out_size, void* d_ws, size_t ws_size,
                              hipStream_t stream) {
  const float* x  = (const float*)d_in[0];
  const float* Wg = (const float*)d_in[1];
  const float* W1 = (const float*)d_in[2];
  const float* b1 = (const float*)d_in[3];
  const float* W2 = (const float*)d_in[4];
  const float* b2 = (const float*)d_in[5];
  float* out = (float*)d_out;
  char* ws = (char*)d_ws;

  unsigned short* W1t = (unsigned short*)(ws + OFF_W1T);
  unsigned short* W2t = (unsigned short*)(ws + OFF_W2T);
  unsigned short* h   = (unsigned short*)(ws + OFF_H);
  int* meta    = (int*)(ws + OFF_META);
  int* counts  = meta;
  int* offsets = meta + 8;
  int* mtile_e = meta + 32;
  unsigned short* xg = (unsigned short*)(ws + OFF_XG);
  float* o       = (float*)(ws + OFF_O);
  int2* tok_e    = (int2*)(ws + OFF_TOKE);
  int2* tok_slot = (int2*)(ws + OFF_TOKSLOT);
  float2* tok_g  = (float2*)(ws + OFF_TOKG);

  hipMemsetAsync(ws + ZERO_START, 0, ZERO_LEN, stream);

  transpose_cast<<<dim3(FDIM / 32, DIM / 32, NEXP), 256, 0, stream>>>(W1, W1t, DIM, FDIM);
  transpose_cast<<<dim3(DIM / 32, FDIM / 32, NEXP), 256, 0, stream>>>(W2, W2t, FDIM, DIM);
  gate_kernel<<<GB, 256, 0, stream>>>(x, Wg, counts, tok_e, tok_slot, tok_g);
  offsets_kernel<<<1, 64, 0, stream>>>(counts, offsets, mtile_e);
  gather_kernel<<<NTOK * 2, 128, 0, stream>>>(x, tok_e, tok_slot, offsets, (ushort4*)xg);
  gemm1_kernel<<<dim3(NMT, FDIM / 128), 256, 0, stream>>>(xg, W1t, mtile_e, b1, h);
  gemm2_kernel<<<dim3(NMT, DIM / 128, KSPLIT), 256, 0, stream>>>(h, W2t, mtile_e, o);
  combine_kernel<<<NTOK, 128, 0, stream>>>(o, tok_e, tok_slot, tok_g, offsets, b2, out);
}

// Round 6
// 331.051 us; speedup vs baseline: 1.1305x; 1.0901x over previous
//
#include <hip/hip_runtime.h>
#include <stdint.h>
#include <math.h>

#define NTOK 8192
#define DIM  512
#define FDIM 2048
#define NEXP 8
#define RMAX 17408   // 136 * 128 >= 2*NTOK + NEXP*127 alignment pad
#define NMT  136
#define KSPLIT 2

typedef __attribute__((ext_vector_type(8))) __bf16 bf16x8;
typedef __attribute__((ext_vector_type(4))) float  f32x4;

// ---------------- workspace layout (bytes), total ~159 MB (proven budget) ----
#define OFF_W1T    ((size_t)0)
#define SZ_W1T     ((size_t)NEXP * DIM * FDIM * 2)   // 16.8 MB
#define OFF_W2T    (OFF_W1T + SZ_W1T)
#define SZ_W2T     SZ_W1T
#define OFF_H      (OFF_W2T + SZ_W2T)
#define SZ_H       ((size_t)RMAX * FDIM * 2)         // 71.3 MB
#define OFF_META   (OFF_H + SZ_H)                    // counts[8] @0, offsets[9] @8, mtile_e[136] @32
#define SZ_META    ((size_t)1024)
#define OFF_XG     (OFF_META + SZ_META)
#define SZ_XG      ((size_t)RMAX * DIM * 2)          // 17.8 MB; o1 (bf16 partial) aliases this
#define OFF_O1     OFF_XG                            // gemm2 runs after gemm1 -> xg dead
#define OFF_O0     (OFF_XG + SZ_XG)
#define SZ_O0      ((size_t)RMAX * DIM * 4)          // 35.7 MB fp32 partial
#define OFF_TOKE   (OFF_O0 + SZ_O0)
#define OFF_TOKSLOT (OFF_TOKE + (size_t)NTOK * 8)
#define OFF_TOKG   (OFF_TOKSLOT + (size_t)NTOK * 8)

__device__ __forceinline__ unsigned short f2bf(float f) {
  union { float f; unsigned int u; } v; v.f = f;
  unsigned int u = v.u;
  return (unsigned short)((u + 0x7fffu + ((u >> 16) & 1u)) >> 16);
}
__device__ __forceinline__ float bf2f(unsigned short u) {
  union { unsigned int u; float f; } v; v.u = ((unsigned int)u) << 16;
  return v.f;
}

// async 16B/lane global->LDS; lds base must be wave-uniform, HW adds lane*16
__device__ __forceinline__ void gld16(const unsigned short* g, unsigned short* l) {
  __builtin_amdgcn_global_load_lds(
      (const __attribute__((address_space(1))) void*)g,
      (__attribute__((address_space(3))) void*)l, 16, 0, 0);
}

// ---------------- transpose + bf16 cast: src [B][R][C] f32 -> dst [B][C][R] bf16 ----------------
__global__ void transpose_cast(const float* __restrict__ src, unsigned short* __restrict__ dst,
                               int R, int C) {
  __shared__ float t[32][33];
  const int b = blockIdx.z;
  const int r0 = blockIdx.y * 32, c0 = blockIdx.x * 32;
  const float* s = src + (size_t)b * R * C;
  unsigned short* d = dst + (size_t)b * R * C;
  const int tr = threadIdx.x >> 5, tc = threadIdx.x & 31;  // tr 0..7
  #pragma unroll
  for (int i = 0; i < 4; i++)
    t[tr + i * 8][tc] = s[(size_t)(r0 + tr + i * 8) * C + (c0 + tc)];
  __syncthreads();
  #pragma unroll
  for (int i = 0; i < 4; i++)
    d[(size_t)(c0 + tr + i * 8) * R + (r0 + tc)] = f2bf(t[tc][tr + i * 8]);
}

// ---------------- gating: fp64 logits, top-2, softmax; hierarchical slot counting ----------------
#define GB 128
#define TPB 64   // tokens per block (4 waves x 16)
__global__ __launch_bounds__(256) void gate_kernel(const float* __restrict__ x,
                            const float* __restrict__ Wg,
                            int* __restrict__ counts, int2* __restrict__ tok_e,
                            int2* __restrict__ tok_slot, float2* __restrict__ tok_g) {
  __shared__ int hist[NEXP];
  __shared__ int base[NEXP];
  __shared__ int le[TPB][2];
  __shared__ int ls[TPB][2];
  __shared__ float lg[TPB][2];
  const int wid = threadIdx.x >> 6;
  const int lane = threadIdx.x & 63;
  if (threadIdx.x < NEXP) hist[threadIdx.x] = 0;
  __syncthreads();
  for (int t = 0; t < 16; t++) {
    const int lt = wid * 16 + t;
    const int n = blockIdx.x * TPB + lt;
    double acc[NEXP];
    #pragma unroll
    for (int e = 0; e < NEXP; e++) acc[e] = 0.0;
    #pragma unroll
    for (int i = 0; i < 8; i++) {
      int dd = lane + i * 64;
      double xv = (double)x[(size_t)n * DIM + dd];
      const float* wr = Wg + (size_t)dd * NEXP;
      #pragma unroll
      for (int e = 0; e < NEXP; e++) acc[e] += xv * (double)wr[e];
    }
    #pragma unroll
    for (int s = 32; s > 0; s >>= 1)
      #pragma unroll
      for (int e = 0; e < NEXP; e++) acc[e] += __shfl_xor(acc[e], s, 64);
    if (lane == 0) {
      int i0 = 0;
      #pragma unroll
      for (int e = 1; e < NEXP; e++) if (acc[e] > acc[i0]) i0 = e;
      int i1 = (i0 == 0) ? 1 : 0;
      #pragma unroll
      for (int e = 0; e < NEXP; e++) { if (e == i0 || e == i1) continue; if (acc[e] > acc[i1]) i1 = e; }
      double e1 = exp(acc[i1] - acc[i0]), ssum = 1.0 + e1;
      le[lt][0] = i0; le[lt][1] = i1;
      ls[lt][0] = atomicAdd(&hist[i0], 1);
      ls[lt][1] = atomicAdd(&hist[i1], 1);
      lg[lt][0] = (float)(1.0 / ssum); lg[lt][1] = (float)(e1 / ssum);
    }
  }
  __syncthreads();
  if (threadIdx.x < NEXP)
    base[threadIdx.x] = atomicAdd(&counts[threadIdx.x], hist[threadIdx.x]);
  __syncthreads();
  if (threadIdx.x < TPB) {
    const int lt = threadIdx.x;
    const int n = blockIdx.x * TPB + lt;
    const int i0 = le[lt][0], i1 = le[lt][1];
    tok_e[n] = make_int2(i0, i1);
    tok_slot[n] = make_int2(base[i0] + ls[lt][0], base[i1] + ls[lt][1]);
    tok_g[n] = make_float2(lg[lt][0], lg[lt][1]);
  }
}

// ---------------- 128-aligned segment offsets + per-M-tile expert id ----------------
__global__ void offsets_kernel(const int* __restrict__ counts, int* __restrict__ offsets,
                               int* __restrict__ mtile_e) {
  if (threadIdx.x == 0 && blockIdx.x == 0) {
    int off = 0;
    for (int e = 0; e < NEXP; e++) { offsets[e] = off; off += (counts[e] + 127) & ~127; }
    offsets[NEXP] = off;
    for (int t = 0; t < NMT; t++) {
      int r = t * 128, e = NEXP - 1;
      for (int q = 0; q < NEXP; q++)
        if (r >= offsets[q] && r < offsets[q + 1]) { e = q; break; }
      mtile_e[t] = e;
    }
  }
}

// ---------------- gather: one block per token, x read once, written to both slots ----------------
__global__ void gather_kernel(const float* __restrict__ x, const int2* __restrict__ tok_e,
                              const int2* __restrict__ tok_slot,
                              const int* __restrict__ offsets, ushort4* __restrict__ xg) {
  const int n = blockIdx.x;
  int2 te = tok_e[n]; int2 ts = tok_slot[n];
  const int r0 = offsets[te.x] + ts.x;
  const int r1 = offsets[te.y] + ts.y;
  const float4* xr = (const float4*)(x + (size_t)n * DIM);
  float4 v = xr[threadIdx.x];
  ushort4 o;
  o.x = f2bf(v.x); o.y = f2bf(v.y); o.z = f2bf(v.z); o.w = f2bf(v.w);
  xg[(size_t)r0 * (DIM / 4) + threadIdx.x] = o;
  xg[(size_t)r1 * (DIM / 4) + threadIdx.x] = o;
}

// ---------------- 128x128xBK64 bf16 MFMA GEMM core, global_load_lds staging ----------------
// BK=64: 8 gld16 + 32 MFMA per barrier pair. XOR chunk swizzle (slot [row][c]
// holds global chunk c^(row&7)); read side 2-way bank aliasing (free).
template <int K, int LDA, int LDB>
__device__ __forceinline__ void gemm_core(const unsigned short* __restrict__ A,
                                          const unsigned short* __restrict__ B,
                                          int m0, int n0, f32x4 acc[4][4]) {
  __shared__ __align__(16) unsigned short As[128 * 64];  // 16 KB
  __shared__ __align__(16) unsigned short Bs[128 * 64];  // 16 KB
  const int tid = threadIdx.x;
  const int wid = tid >> 6, lane = tid & 63;
  const int wm = (wid >> 1) * 64, wn = (wid & 1) * 64;
  const int quad = lane >> 4, l16 = lane & 15;
  const int srow = tid >> 3;                        // 0..31
  const int scol = ((tid & 7) ^ (srow & 7)) << 3;   // swizzled source chunk (elems)
  unsigned short* As_w = As + 512 * wid;            // wave-uniform base (16B*64 per wave)
  unsigned short* Bs_w = Bs + 512 * wid;
  const int r7 = (l16 & 7) << 3;                    // read-side swizzle key (elems)
  const unsigned short* Ar = A + (size_t)(m0 + srow) * LDA + scol;
  const unsigned short* Br = B + (size_t)(n0 + srow) * LDB + scol;
  #pragma unroll 1
  for (int kt = 0; kt < K; kt += 64) {
    __syncthreads();                      // prior iteration's LDS reads done
    #pragma unroll
    for (int p = 0; p < 4; p++) {
      gld16(Ar + (size_t)(32 * p) * LDA + kt, As_w + p * 2048);
      gld16(Br + (size_t)(32 * p) * LDB + kt, Bs_w + p * 2048);
    }
    __syncthreads();                      // drains vmcnt before ds_read
    #pragma unroll
    for (int kk = 0; kk < 2; kk++) {
      const int swz = ((kk * 4 + quad) << 3) ^ r7;  // swizzled chunk offset (elems)
      bf16x8 af[4], bfr[4];
      #pragma unroll
      for (int i = 0; i < 4; i++) {
        af[i]  = *(const bf16x8*)(As + (wm + i * 16 + l16) * 64 + swz);
        bfr[i] = *(const bf16x8*)(Bs + (wn + i * 16 + l16) * 64 + swz);
      }
      #pragma unroll
      for (int mi = 0; mi < 4; mi++)
        #pragma unroll
        for (int ni = 0; ni < 4; ni++)
          acc[mi][ni] = __builtin_amdgcn_mfma_f32_16x16x32_bf16(af[mi], bfr[ni], acc[mi][ni], 0, 0, 0);
    }
  }
}

// ---------------- GEMM1: h = relu(xg @ W1[e] + b1[e]) -> bf16 ----------------
__global__ __launch_bounds__(256) void gemm1_kernel(const unsigned short* __restrict__ xg,
    const unsigned short* __restrict__ W1t, const int* __restrict__ mtile_e,
    const float* __restrict__ b1, unsigned short* __restrict__ h) {
  const int bm = blockIdx.x, bn = blockIdx.y;
  const int e = mtile_e[bm];
  f32x4 acc[4][4];
  #pragma unroll
  for (int i = 0; i < 4; i++)
    #pragma unroll
    for (int j = 0; j < 4; j++) acc[i][j] = (f32x4){0.f, 0.f, 0.f, 0.f};
  gemm_core<DIM, DIM, DIM>(xg, W1t + (size_t)e * FDIM * DIM, bm * 128, bn * 128, acc);
  const int tid = threadIdx.x, wid = tid >> 6, lane = tid & 63;
  const int wm = (wid >> 1) * 64, wn = (wid & 1) * 64, quad = lane >> 4, l16 = lane & 15;
  #pragma unroll
  for (int mi = 0; mi < 4; mi++) {
    #pragma unroll
    for (int ni = 0; ni < 4; ni++) {
      const int col = bn * 128 + wn + ni * 16 + l16;
      const float bb = b1[e * FDIM + col];
      #pragma unroll
      for (int r = 0; r < 4; r++) {
        const int row = bm * 128 + wm + mi * 16 + quad * 4 + r;
        float v = acc[mi][ni][r] + bb;
        h[(size_t)row * FDIM + col] = f2bf(v > 0.f ? v : 0.f);
      }
    }
  }
}

// ---------------- GEMM2 (split-K, deterministic): ks=0 -> o0 fp32, ks=1 -> o1 bf16 ----------------
__global__ __launch_bounds__(256) void gemm2_kernel(const unsigned short* __restrict__ h,
    const unsigned short* __restrict__ W2t, const int* __restrict__ mtile_e,
    float* __restrict__ o0, unsigned short* __restrict__ o1) {
  const int bm = blockIdx.x, bn = blockIdx.y, ks = blockIdx.z;
  const int e = mtile_e[bm];
  const int k0 = ks * (FDIM / KSPLIT);
  f32x4 acc[4][4];
  #pragma unroll
  for (int i = 0; i < 4; i++)
    #pragma unroll
    for (int j = 0; j < 4; j++) acc[i][j] = (f32x4){0.f, 0.f, 0.f, 0.f};
  gemm_core<FDIM / KSPLIT, FDIM, FDIM>(h + k0, W2t + (size_t)e * DIM * FDIM + k0,
                                       bm * 128, bn * 128, acc);
  const int tid = threadIdx.x, wid = tid >> 6, lane = tid & 63;
  const int wm = (wid >> 1) * 64, wn = (wid & 1) * 64, quad = lane >> 4, l16 = lane & 15;
  if (ks == 0) {
    #pragma unroll
    for (int mi = 0; mi < 4; mi++)
      #pragma unroll
      for (int r = 0; r < 4; r++) {
        const int row = bm * 128 + wm + mi * 16 + quad * 4 + r;
        #pragma unroll
        for (int ni = 0; ni < 4; ni++) {
          const int col = bn * 128 + wn + ni * 16 + l16;
          o0[(size_t)row * DIM + col] = acc[mi][ni][r];
        }
      }
  } else {
    #pragma unroll
    for (int mi = 0; mi < 4; mi++)
      #pragma unroll
      for (int r = 0; r < 4; r++) {
        const int row = bm * 128 + wm + mi * 16 + quad * 4 + r;
        #pragma unroll
        for (int ni = 0; ni < 4; ni++) {
          const int col = bn * 128 + wn + ni * 16 + l16;
          o1[(size_t)row * DIM + col] = f2bf(acc[mi][ni][r]);
        }
      }
  }
}

// ---------------- combine: out[n] = log(g0*exp(o(r0)+b2[e0]) + g1*exp(o(r1)+b2[e1])) ----------------
__global__ void combine_kernel(const float* __restrict__ o0, const unsigned short* __restrict__ o1,
                               const int2* __restrict__ tok_e,
                               const int2* __restrict__ tok_slot, const float2* __restrict__ tok_g,
                               const int* __restrict__ offsets, const float* __restrict__ b2,
                               float* __restrict__ out) {
  const int n = blockIdx.x;
  const int c = threadIdx.x * 4;  // 128 threads x float4
  int2 te = tok_e[n]; int2 ts = tok_slot[n]; float2 tg = tok_g[n];
  const int r0 = offsets[te.x] + ts.x;
  const int r1 = offsets[te.y] + ts.y;
  float4 a0 = *(const float4*)(o0 + (size_t)r0 * DIM + c);
  float4 a1 = *(const float4*)(o0 + (size_t)r1 * DIM + c);
  ushort4 p0 = *(const ushort4*)(o1 + (size_t)r0 * DIM + c);
  ushort4 p1 = *(const ushort4*)(o1 + (size_t)r1 * DIM + c);
  float4 c0 = *(const float4*)(b2 + te.x * DIM + c);
  float4 c1 = *(const float4*)(b2 + te.y * DIM + c);
  float4 res;
  #pragma unroll
  for (int j = 0; j < 4; j++) {
    float v0 = ((const float*)&a0)[j] + bf2f(((const unsigned short*)&p0)[j]) + ((const float*)&c0)[j];
    float v1 = ((const float*)&a1)[j] + bf2f(((const unsigned short*)&p1)[j]) + ((const float*)&c1)[j];
    float v = tg.x * expf(v0) + tg.y * expf(v1);
    v = (v == 0.0f) ? 2.220446049250313e-16f : v;
    ((float*)&res)[j] = logf(v);
  }
  *(float4*)(out + (size_t)n * DIM + c) = res;
}

extern "C" void kernel_launch(void* const* d_in, const int* in_sizes, int n_in,
                              void* d_out, int out_size, void* d_ws, size_t ws_size,
                              hipStream_t stream) {
  const float* x  = (const float*)d_in[0];
  const float* Wg = (const float*)d_in[1];
  const float* W1 = (const float*)d_in[2];
  const float* b1 = (const float*)d_in[3];
  const float* W2 = (const float*)d_in[4];
  const float* b2 = (const float*)d_in[5];
  float* out = (float*)d_out;
  char* ws = (char*)d_ws;

  unsigned short* W1t = (unsigned short*)(ws + OFF_W1T);
  unsigned short* W2t = (unsigned short*)(ws + OFF_W2T);
  unsigned short* h   = (unsigned short*)(ws + OFF_H);
  int* meta    = (int*)(ws + OFF_META);
  int* counts  = meta;
  int* offsets = meta + 8;
  int* mtile_e = meta + 32;
  unsigned short* xg = (unsigned short*)(ws + OFF_XG);
  unsigned short* o1 = (unsigned short*)(ws + OFF_O1);  // aliases xg (dead after gemm1)
  float* o0      = (float*)(ws + OFF_O0);
  int2* tok_e    = (int2*)(ws + OFF_TOKE);
  int2* tok_slot = (int2*)(ws + OFF_TOKSLOT);
  float2* tok_g  = (float2*)(ws + OFF_TOKG);

  hipMemsetAsync(ws + OFF_META, 0, SZ_META, stream);  // counts only; pads never read

  transpose_cast<<<dim3(FDIM / 32, DIM / 32, NEXP), 256, 0, stream>>>(W1, W1t, DIM, FDIM);
  transpose_cast<<<dim3(DIM / 32, FDIM / 32, NEXP), 256, 0, stream>>>(W2, W2t, FDIM, DIM);
  gate_kernel<<<GB, 256, 0, stream>>>(x, Wg, counts, tok_e, tok_slot, tok_g);
  offsets_kernel<<<1, 64, 0, stream>>>(counts, offsets, mtile_e);
  gather_kernel<<<NTOK, 128, 0, stream>>>(x, tok_e, tok_slot, offsets, (ushort4*)xg);
  gemm1_kernel<<<dim3(NMT, FDIM / 128), 256, 0, stream>>>(xg, W1t, mtile_e, b1, h);
  gemm2_kernel<<<dim3(NMT, DIM / 128, KSPLIT), 256, 0, stream>>>(h, W2t, mtile_e, o0, o1);
  combine_kernel<<<NTOK, 128, 0, stream>>>(o0, o1, tok_e, tok_slot, tok_g, offsets, b2, out);
}

// Round 7
// 330.766 us; speedup vs baseline: 1.1315x; 1.0009x over previous
//
#include <hip/hip_runtime.h>
#include <stdint.h>
#include <math.h>

#define NTOK 8192
#define DIM  512
#define FDIM 2048
#define NEXP 8
#define RMAX 17408   // 136 * 128 >= 2*NTOK + NEXP*127 alignment pad
#define NMT  136
#define KSPLIT 2

typedef __attribute__((ext_vector_type(8))) __bf16 bf16x8;
typedef __attribute__((ext_vector_type(4))) float  f32x4;

// ---------------- workspace layout (bytes), total ~159 MB (proven budget) ----
#define OFF_W1T    ((size_t)0)
#define SZ_W1T     ((size_t)NEXP * DIM * FDIM * 2)   // 16.8 MB
#define OFF_W2T    (OFF_W1T + SZ_W1T)
#define SZ_W2T     SZ_W1T
#define OFF_H      (OFF_W2T + SZ_W2T)
#define SZ_H       ((size_t)RMAX * FDIM * 2)         // 71.3 MB
#define OFF_META   (OFF_H + SZ_H)                    // counts[8] @0, offsets[9] @8, mtile_e[136] @32
#define SZ_META    ((size_t)1024)
#define OFF_XG     (OFF_META + SZ_META)
#define SZ_XG      ((size_t)RMAX * DIM * 2)          // 17.8 MB; o1 (bf16 partial) aliases this
#define OFF_O1     OFF_XG                            // gemm2 runs after gemm1 -> xg dead
#define OFF_O0     (OFF_XG + SZ_XG)
#define SZ_O0      ((size_t)RMAX * DIM * 4)          // 35.7 MB fp32 partial
#define OFF_TOKE   (OFF_O0 + SZ_O0)
#define OFF_TOKSLOT (OFF_TOKE + (size_t)NTOK * 8)
#define OFF_TOKG   (OFF_TOKSLOT + (size_t)NTOK * 8)

// prep-kernel grid partition
#define PREP_TBLK 8192
#define PREP_GATE (2 * PREP_TBLK)
#define TPB 64                    // gate tokens per block (4 waves x 16)
#define GB_BLOCKS (NTOK / TPB)    // 128 gate blocks

__device__ __forceinline__ unsigned short f2bf(float f) {
  union { float f; unsigned int u; } v; v.f = f;
  unsigned int u = v.u;
  return (unsigned short)((u + 0x7fffu + ((u >> 16) & 1u)) >> 16);
}
__device__ __forceinline__ float bf2f(unsigned short u) {
  union { unsigned int u; float f; } v; v.u = ((unsigned int)u) << 16;
  return v.f;
}

// async 16B/lane global->LDS; lds base must be wave-uniform, HW adds lane*16
__device__ __forceinline__ void gld16(const unsigned short* g, unsigned short* l) {
  __builtin_amdgcn_global_load_lds(
      (const __attribute__((address_space(1))) void*)g,
      (__attribute__((address_space(3))) void*)l, 16, 0, 0);
}

// ---------------- fused prep: transpose W1 | transpose W2 | gate ----------------
__device__ __forceinline__ void transpose_tile(const float* __restrict__ src,
                                               unsigned short* __restrict__ dst,
                                               int R, int C, int bx, int by, int bz) {
  __shared__ float t[32][33];
  const int r0 = by * 32, c0 = bx * 32;
  const float* s = src + (size_t)bz * R * C;
  unsigned short* d = dst + (size_t)bz * R * C;
  const int tr = threadIdx.x >> 5, tc = threadIdx.x & 31;  // tr 0..7
  #pragma unroll
  for (int i = 0; i < 4; i++)
    t[tr + i * 8][tc] = s[(size_t)(r0 + tr + i * 8) * C + (c0 + tc)];
  __syncthreads();
  #pragma unroll
  for (int i = 0; i < 4; i++)
    d[(size_t)(c0 + tr + i * 8) * R + (r0 + tc)] = f2bf(t[tc][tr + i * 8]);
}

__device__ __forceinline__ void gate_body(int gb, const float* __restrict__ x,
                            const float* __restrict__ Wg,
                            int* __restrict__ counts, int2* __restrict__ tok_e,
                            int2* __restrict__ tok_slot, float2* __restrict__ tok_g) {
  __shared__ int hist[NEXP];
  __shared__ int base[NEXP];
  __shared__ int le[TPB][2];
  __shared__ int ls[TPB][2];
  __shared__ float lg[TPB][2];
  const int wid = threadIdx.x >> 6;
  const int lane = threadIdx.x & 63;
  if (threadIdx.x < NEXP) hist[threadIdx.x] = 0;
  __syncthreads();
  for (int t = 0; t < 16; t++) {
    const int lt = wid * 16 + t;
    const int n = gb * TPB + lt;
    double acc[NEXP];
    #pragma unroll
    for (int e = 0; e < NEXP; e++) acc[e] = 0.0;
    #pragma unroll
    for (int i = 0; i < 8; i++) {
      int dd = lane + i * 64;
      double xv = (double)x[(size_t)n * DIM + dd];
      const float* wr = Wg + (size_t)dd * NEXP;
      #pragma unroll
      for (int e = 0; e < NEXP; e++) acc[e] += xv * (double)wr[e];
    }
    #pragma unroll
    for (int s = 32; s > 0; s >>= 1)
      #pragma unroll
      for (int e = 0; e < NEXP; e++) acc[e] += __shfl_xor(acc[e], s, 64);
    if (lane == 0) {
      int i0 = 0;
      #pragma unroll
      for (int e = 1; e < NEXP; e++) if (acc[e] > acc[i0]) i0 = e;
      int i1 = (i0 == 0) ? 1 : 0;
      #pragma unroll
      for (int e = 0; e < NEXP; e++) { if (e == i0 || e == i1) continue; if (acc[e] > acc[i1]) i1 = e; }
      double e1 = exp(acc[i1] - acc[i0]), ssum = 1.0 + e1;
      le[lt][0] = i0; le[lt][1] = i1;
      ls[lt][0] = atomicAdd(&hist[i0], 1);
      ls[lt][1] = atomicAdd(&hist[i1], 1);
      lg[lt][0] = (float)(1.0 / ssum); lg[lt][1] = (float)(e1 / ssum);
    }
  }
  __syncthreads();
  if (threadIdx.x < NEXP)
    base[threadIdx.x] = atomicAdd(&counts[threadIdx.x], hist[threadIdx.x]);
  __syncthreads();
  if (threadIdx.x < TPB) {
    const int lt = threadIdx.x;
    const int n = gb * TPB + lt;
    const int i0 = le[lt][0], i1 = le[lt][1];
    tok_e[n] = make_int2(i0, i1);
    tok_slot[n] = make_int2(base[i0] + ls[lt][0], base[i1] + ls[lt][1]);
    tok_g[n] = make_float2(lg[lt][0], lg[lt][1]);
  }
}

__global__ __launch_bounds__(256) void prep_kernel(const float* __restrict__ W1,
    unsigned short* __restrict__ W1t, const float* __restrict__ W2,
    unsigned short* __restrict__ W2t, const float* __restrict__ x,
    const float* __restrict__ Wg, int* __restrict__ counts, int2* __restrict__ tok_e,
    int2* __restrict__ tok_slot, float2* __restrict__ tok_g) {
  const int b = blockIdx.x;
  if (b < PREP_TBLK) {             // W1: R=512, C=2048 -> 64 x 16 x 8 tiles
    transpose_tile(W1, W1t, DIM, FDIM, b & 63, (b >> 6) & 15, b >> 10);
  } else if (b < PREP_GATE) {      // W2: R=2048, C=512 -> 16 x 64 x 8 tiles
    const int q = b - PREP_TBLK;
    transpose_tile(W2, W2t, FDIM, DIM, q & 15, (q >> 4) & 63, q >> 10);
  } else {
    gate_body(b - PREP_GATE, x, Wg, counts, tok_e, tok_slot, tok_g);
  }
}

// ---------------- 128-aligned segment offsets + per-M-tile expert id ----------------
__global__ void offsets_kernel(const int* __restrict__ counts, int* __restrict__ offsets,
                               int* __restrict__ mtile_e) {
  if (threadIdx.x == 0 && blockIdx.x == 0) {
    int off = 0;
    for (int e = 0; e < NEXP; e++) { offsets[e] = off; off += (counts[e] + 127) & ~127; }
    offsets[NEXP] = off;
    for (int t = 0; t < NMT; t++) {
      int r = t * 128, e = NEXP - 1;
      for (int q = 0; q < NEXP; q++)
        if (r >= offsets[q] && r < offsets[q + 1]) { e = q; break; }
      mtile_e[t] = e;
    }
  }
}

// ---------------- gather: one block per token, x read once, written to both slots ----------------
__global__ void gather_kernel(const float* __restrict__ x, const int2* __restrict__ tok_e,
                              const int2* __restrict__ tok_slot,
                              const int* __restrict__ offsets, ushort4* __restrict__ xg) {
  const int n = blockIdx.x;
  int2 te = tok_e[n]; int2 ts = tok_slot[n];
  const int r0 = offsets[te.x] + ts.x;
  const int r1 = offsets[te.y] + ts.y;
  const float4* xr = (const float4*)(x + (size_t)n * DIM);
  float4 v = xr[threadIdx.x];
  ushort4 o;
  o.x = f2bf(v.x); o.y = f2bf(v.y); o.z = f2bf(v.z); o.w = f2bf(v.w);
  xg[(size_t)r0 * (DIM / 4) + threadIdx.x] = o;
  xg[(size_t)r1 * (DIM / 4) + threadIdx.x] = o;
}

// ---------------- 128x128xBK64 bf16 MFMA GEMM core, global_load_lds staging ----------------
// BK=64: 8 gld16 + 32 MFMA per barrier pair. XOR chunk swizzle (slot [row][c]
// holds global chunk c^(row&7)); read side 2-way bank aliasing (free).
// Register-dieted for __launch_bounds__(256,4): 2 base pointers, folded offsets.
template <int K, int LDA, int LDB>
__device__ __forceinline__ void gemm_core(const unsigned short* __restrict__ A,
                                          const unsigned short* __restrict__ B,
                                          int m0, int n0, f32x4 acc[4][4]) {
  __shared__ __align__(16) unsigned short As[128 * 64];  // 16 KB
  __shared__ __align__(16) unsigned short Bs[128 * 64];  // 16 KB
  const int tid = threadIdx.x;
  const int wid = tid >> 6, lane = tid & 63;
  const int wm = (wid >> 1) * 64, wn = (wid & 1) * 64;
  const int quad = lane >> 4, l16 = lane & 15;
  const int srow = tid >> 3;                        // 0..31
  const int scol = ((tid & 7) ^ (srow & 7)) << 3;   // swizzled source chunk (elems)
  unsigned short* As_w = As + 512 * wid;            // wave-uniform base (16B*64 per wave)
  unsigned short* Bs_w = Bs + 512 * wid;
  const int r7 = (l16 & 7) << 3;                    // read-side swizzle key (elems)
  const unsigned short* Ar = A + (size_t)(m0 + srow) * LDA + scol;
  const unsigned short* Br = B + (size_t)(n0 + srow) * LDB + scol;
  #pragma unroll 1
  for (int kt = 0; kt < K; kt += 64) {
    __syncthreads();                      // prior iteration's LDS reads done
    #pragma unroll
    for (int p = 0; p < 4; p++) {
      gld16(Ar + (size_t)(32 * p) * LDA + kt, As_w + p * 2048);
      gld16(Br + (size_t)(32 * p) * LDB + kt, Bs_w + p * 2048);
    }
    __syncthreads();                      // drains vmcnt before ds_read
    #pragma unroll
    for (int kk = 0; kk < 2; kk++) {
      const int swz = ((kk * 4 + quad) << 3) ^ r7;  // swizzled chunk offset (elems)
      bf16x8 af[4], bfr[4];
      #pragma unroll
      for (int i = 0; i < 4; i++) {
        af[i]  = *(const bf16x8*)(As + (wm + i * 16 + l16) * 64 + swz);
        bfr[i] = *(const bf16x8*)(Bs + (wn + i * 16 + l16) * 64 + swz);
      }
      #pragma unroll
      for (int mi = 0; mi < 4; mi++)
        #pragma unroll
        for (int ni = 0; ni < 4; ni++)
          acc[mi][ni] = __builtin_amdgcn_mfma_f32_16x16x32_bf16(af[mi], bfr[ni], acc[mi][ni], 0, 0, 0);
    }
  }
}

// ---------------- GEMM1: h = relu(xg @ W1[e] + b1[e]) -> bf16 ----------------
__global__ __launch_bounds__(256, 4) void gemm1_kernel(const unsigned short* __restrict__ xg,
    const unsigned short* __restrict__ W1t, const int* __restrict__ mtile_e,
    const float* __restrict__ b1, unsigned short* __restrict__ h) {
  const int bm = blockIdx.x, bn = blockIdx.y;
  const int e = mtile_e[bm];
  f32x4 acc[4][4];
  #pragma unroll
  for (int i = 0; i < 4; i++)
    #pragma unroll
    for (int j = 0; j < 4; j++) acc[i][j] = (f32x4){0.f, 0.f, 0.f, 0.f};
  gemm_core<DIM, DIM, DIM>(xg, W1t + (size_t)e * FDIM * DIM, bm * 128, bn * 128, acc);
  const int tid = threadIdx.x, wid = tid >> 6, lane = tid & 63;
  const int wm = (wid >> 1) * 64, wn = (wid & 1) * 64, quad = lane >> 4, l16 = lane & 15;
  #pragma unroll
  for (int mi = 0; mi < 4; mi++) {
    #pragma unroll
    for (int ni = 0; ni < 4; ni++) {
      const int col = bn * 128 + wn + ni * 16 + l16;
      const float bb = b1[e * FDIM + col];
      #pragma unroll
      for (int r = 0; r < 4; r++) {
        const int row = bm * 128 + wm + mi * 16 + quad * 4 + r;
        float v = acc[mi][ni][r] + bb;
        h[(size_t)row * FDIM + col] = f2bf(v > 0.f ? v : 0.f);
      }
    }
  }
}

// ---------------- GEMM2 (split-K, deterministic): ks=0 -> o0 fp32, ks=1 -> o1 bf16 ----------------
__global__ __launch_bounds__(256, 4) void gemm2_kernel(const unsigned short* __restrict__ h,
    const unsigned short* __restrict__ W2t, const int* __restrict__ mtile_e,
    float* __restrict__ o0, unsigned short* __restrict__ o1) {
  const int bm = blockIdx.x, bn = blockIdx.y, ks = blockIdx.z;
  const int e = mtile_e[bm];
  const int k0 = ks * (FDIM / KSPLIT);
  f32x4 acc[4][4];
  #pragma unroll
  for (int i = 0; i < 4; i++)
    #pragma unroll
    for (int j = 0; j < 4; j++) acc[i][j] = (f32x4){0.f, 0.f, 0.f, 0.f};
  gemm_core<FDIM / KSPLIT, FDIM, FDIM>(h + k0, W2t + (size_t)e * DIM * FDIM + k0,
                                       bm * 128, bn * 128, acc);
  const int tid = threadIdx.x, wid = tid >> 6, lane = tid & 63;
  const int wm = (wid >> 1) * 64, wn = (wid & 1) * 64, quad = lane >> 4, l16 = lane & 15;
  if (ks == 0) {
    #pragma unroll
    for (int mi = 0; mi < 4; mi++)
      #pragma unroll
      for (int r = 0; r < 4; r++) {
        const int row = bm * 128 + wm + mi * 16 + quad * 4 + r;
        #pragma unroll
        for (int ni = 0; ni < 4; ni++) {
          const int col = bn * 128 + wn + ni * 16 + l16;
          o0[(size_t)row * DIM + col] = acc[mi][ni][r];
        }
      }
  } else {
    #pragma unroll
    for (int mi = 0; mi < 4; mi++)
      #pragma unroll
      for (int r = 0; r < 4; r++) {
        const int row = bm * 128 + wm + mi * 16 + quad * 4 + r;
        #pragma unroll
        for (int ni = 0; ni < 4; ni++) {
          const int col = bn * 128 + wn + ni * 16 + l16;
          o1[(size_t)row * DIM + col] = f2bf(acc[mi][ni][r]);
        }
      }
  }
}

// ---------------- combine: out[n] = log(g0*exp(o(r0)+b2[e0]) + g1*exp(o(r1)+b2[e1])) ----------------
__global__ void combine_kernel(const float* __restrict__ o0, const unsigned short* __restrict__ o1,
                               const int2* __restrict__ tok_e,
                               const int2* __restrict__ tok_slot, const float2* __restrict__ tok_g,
                               const int* __restrict__ offsets, const float* __restrict__ b2,
                               float* __restrict__ out) {
  const int n = blockIdx.x;
  const int c = threadIdx.x * 4;  // 128 threads x float4
  int2 te = tok_e[n]; int2 ts = tok_slot[n]; float2 tg = tok_g[n];
  const int r0 = offsets[te.x] + ts.x;
  const int r1 = offsets[te.y] + ts.y;
  float4 a0 = *(const float4*)(o0 + (size_t)r0 * DIM + c);
  float4 a1 = *(const float4*)(o0 + (size_t)r1 * DIM + c);
  ushort4 p0 = *(const ushort4*)(o1 + (size_t)r0 * DIM + c);
  ushort4 p1 = *(const ushort4*)(o1 + (size_t)r1 * DIM + c);
  float4 c0 = *(const float4*)(b2 + te.x * DIM + c);
  float4 c1 = *(const float4*)(b2 + te.y * DIM + c);
  float4 res;
  #pragma unroll
  for (int j = 0; j < 4; j++) {
    float v0 = ((const float*)&a0)[j] + bf2f(((const unsigned short*)&p0)[j]) + ((const float*)&c0)[j];
    float v1 = ((const float*)&a1)[j] + bf2f(((const unsigned short*)&p1)[j]) + ((const float*)&c1)[j];
    float v = tg.x * expf(v0) + tg.y * expf(v1);
    v = (v == 0.0f) ? 2.220446049250313e-16f : v;
    ((float*)&res)[j] = logf(v);
  }
  *(float4*)(out + (size_t)n * DIM + c) = res;
}

extern "C" void kernel_launch(void* const* d_in, const int* in_sizes, int n_in,
                              void* d_out, int out_size, void* d_ws, size_t ws_size,
                              hipStream_t stream) {
  const float* x  = (const float*)d_in[0];
  const float* Wg = (const float*)d_in[1];
  const float* W1 = (const float*)d_in[2];
  const float* b1 = (const float*)d_in[3];
  const float* W2 = (const float*)d_in[4];
  const float* b2 = (const float*)d_in[5];
  float* out = (float*)d_out;
  char* ws = (char*)d_ws;

  unsigned short* W1t = (unsigned short*)(ws + OFF_W1T);
  unsigned short* W2t = (unsigned short*)(ws + OFF_W2T);
  unsigned short* h   = (unsigned short*)(ws + OFF_H);
  int* meta    = (int*)(ws + OFF_META);
  int* counts  = meta;
  int* offsets = meta + 8;
  int* mtile_e = meta + 32;
  unsigned short* xg = (unsigned short*)(ws + OFF_XG);
  unsigned short* o1 = (unsigned short*)(ws + OFF_O1);  // aliases xg (dead after gemm1)
  float* o0      = (float*)(ws + OFF_O0);
  int2* tok_e    = (int2*)(ws + OFF_TOKE);
  int2* tok_slot = (int2*)(ws + OFF_TOKSLOT);
  float2* tok_g  = (float2*)(ws + OFF_TOKG);

  hipMemsetAsync(ws + OFF_META, 0, SZ_META, stream);  // counts only; pads never read

  prep_kernel<<<PREP_GATE + GB_BLOCKS, 256, 0, stream>>>(W1, W1t, W2, W2t, x, Wg,
                                                         counts, tok_e, tok_slot, tok_g);
  offsets_kernel<<<1, 64, 0, stream>>>(counts, offsets, mtile_e);
  gather_kernel<<<NTOK, 128, 0, stream>>>(x, tok_e, tok_slot, offsets, (ushort4*)xg);
  gemm1_kernel<<<dim3(NMT, FDIM / 128), 256, 0, stream>>>(xg, W1t, mtile_e, b1, h);
  gemm2_kernel<<<dim3(NMT, DIM / 128, KSPLIT), 256, 0, stream>>>(h, W2t, mtile_e, o0, o1);
  combine_kernel<<<NTOK, 128, 0, stream>>>(o0, o1, tok_e, tok_slot, tok_g, offsets, b2, out);
}

// Round 8
// 283.657 us; speedup vs baseline: 1.3194x; 1.1661x over previous
//
#include <hip/hip_runtime.h>
#include <stdint.h>
#include <math.h>

#define NTOK 8192
#define DIM  512
#define FDIM 2048
#define NEXP 8
#define RMAX 17408   // 136 * 128 >= 2*NTOK + NEXP*127 alignment pad
#define NMT  136
#define KSPLIT 2

typedef __attribute__((ext_vector_type(8))) __bf16 bf16x8;
typedef __attribute__((ext_vector_type(4))) float  f32x4;

// ---------------- gate / prep partition ----------------
#define GTPB 16                    // gate tokens per block (4 waves x 4 sequential)
#define GB_BLOCKS (NTOK / GTPB)    // 512 gate blocks, atomic-free
#define PREP_W1 (GB_BLOCKS)        // [512, 512+8192): W1 tiles
#define PREP_W2 (GB_BLOCKS + 8192) // [8704, 16896): W2 tiles

// ---------------- workspace layout (bytes) ----------------
#define OFF_W1T    ((size_t)0)
#define SZ_W1T     ((size_t)NEXP * DIM * FDIM * 2)   // 16.8 MB
#define OFF_W2T    (OFF_W1T + SZ_W1T)
#define SZ_W2T     SZ_W1T
#define OFF_H      (OFF_W2T + SZ_W2T)
#define SZ_H       ((size_t)RMAX * FDIM * 2)         // 71.3 MB
#define OFF_META   (OFF_H + SZ_H)                    // offsets[9] @0, mtile_e[136] @16
#define SZ_META    ((size_t)1024)
#define OFF_XG     (OFF_META + SZ_META)
#define SZ_XG      ((size_t)RMAX * DIM * 2)          // 17.8 MB; o1 (bf16 partial) aliases this
#define OFF_O1     OFF_XG                            // gemm2 runs after gemm1 -> xg dead
#define OFF_O0     (OFF_XG + SZ_XG)
#define SZ_O0      ((size_t)RMAX * DIM * 4)          // 35.7 MB fp32 partial
#define OFF_TOKE   (OFF_O0 + SZ_O0)
#define OFF_TOKLS  (OFF_TOKE + (size_t)NTOK * 8)
#define OFF_TOKG   (OFF_TOKLS + (size_t)NTOK * 8)
#define OFF_HISTP  (OFF_TOKG + (size_t)NTOK * 8)     // [512][8] int
#define OFF_BASEP  (OFF_HISTP + (size_t)GB_BLOCKS * NEXP * 4)
#define OFF_ROWS   (OFF_BASEP + (size_t)GB_BLOCKS * NEXP * 4)  // [NTOK] int2

__device__ __forceinline__ unsigned short f2bf(float f) {
  union { float f; unsigned int u; } v; v.f = f;
  unsigned int u = v.u;
  return (unsigned short)((u + 0x7fffu + ((u >> 16) & 1u)) >> 16);
}
__device__ __forceinline__ float bf2f(unsigned short u) {
  union { unsigned int u; float f; } v; v.u = ((unsigned int)u) << 16;
  return v.f;
}

// async 16B/lane global->LDS; lds base must be wave-uniform, HW adds lane*16
__device__ __forceinline__ void gld16(const unsigned short* g, unsigned short* l) {
  __builtin_amdgcn_global_load_lds(
      (const __attribute__((address_space(1))) void*)g,
      (__attribute__((address_space(3))) void*)l, 16, 0, 0);
}

// ---------------- fused prep: gate (front) | transpose W1 | transpose W2 ----------------
__device__ __forceinline__ void transpose_tile(const float* __restrict__ src,
                                               unsigned short* __restrict__ dst,
                                               int R, int C, int bx, int by, int bz) {
  __shared__ float t[32][33];
  const int r0 = by * 32, c0 = bx * 32;
  const float* s = src + (size_t)bz * R * C;
  unsigned short* d = dst + (size_t)bz * R * C;
  const int tr = threadIdx.x >> 5, tc = threadIdx.x & 31;  // tr 0..7
  #pragma unroll
  for (int i = 0; i < 4; i++)
    t[tr + i * 8][tc] = s[(size_t)(r0 + tr + i * 8) * C + (c0 + tc)];
  __syncthreads();
  #pragma unroll
  for (int i = 0; i < 4; i++)
    d[(size_t)(c0 + tr + i * 8) * R + (r0 + tc)] = f2bf(t[tc][tr + i * 8]);
}

// fp64 logits, top-2, softmax; per-block histogram written to hist_part (NO global atomics)
__device__ __forceinline__ void gate_body(int gb, const float* __restrict__ x,
                            const float* __restrict__ Wg,
                            int* __restrict__ hist_part, int2* __restrict__ tok_e,
                            int2* __restrict__ tok_ls, float2* __restrict__ tok_g) {
  __shared__ int hist[NEXP];
  __shared__ int le[GTPB][2];
  __shared__ int ls[GTPB][2];
  __shared__ float lg[GTPB][2];
  const int wid = threadIdx.x >> 6;
  const int lane = threadIdx.x & 63;
  if (threadIdx.x < NEXP) hist[threadIdx.x] = 0;
  __syncthreads();
  for (int t = 0; t < 4; t++) {
    const int lt = wid * 4 + t;
    const int n = gb * GTPB + lt;
    double acc[NEXP];
    #pragma unroll
    for (int e = 0; e < NEXP; e++) acc[e] = 0.0;
    #pragma unroll
    for (int i = 0; i < 8; i++) {
      int dd = lane + i * 64;
      double xv = (double)x[(size_t)n * DIM + dd];
      const float* wr = Wg + (size_t)dd * NEXP;
      #pragma unroll
      for (int e = 0; e < NEXP; e++) acc[e] += xv * (double)wr[e];
    }
    #pragma unroll
    for (int s = 32; s > 0; s >>= 1)
      #pragma unroll
      for (int e = 0; e < NEXP; e++) acc[e] += __shfl_xor(acc[e], s, 64);
    if (lane == 0) {
      int i0 = 0;
      #pragma unroll
      for (int e = 1; e < NEXP; e++) if (acc[e] > acc[i0]) i0 = e;
      int i1 = (i0 == 0) ? 1 : 0;
      #pragma unroll
      for (int e = 0; e < NEXP; e++) { if (e == i0 || e == i1) continue; if (acc[e] > acc[i1]) i1 = e; }
      double e1 = exp(acc[i1] - acc[i0]), ssum = 1.0 + e1;
      le[lt][0] = i0; le[lt][1] = i1;
      ls[lt][0] = atomicAdd(&hist[i0], 1);
      ls[lt][1] = atomicAdd(&hist[i1], 1);
      lg[lt][0] = (float)(1.0 / ssum); lg[lt][1] = (float)(e1 / ssum);
    }
  }
  __syncthreads();
  if (threadIdx.x < NEXP) hist_part[gb * NEXP + threadIdx.x] = hist[threadIdx.x];
  if (threadIdx.x < GTPB) {
    const int lt = threadIdx.x;
    const int n = gb * GTPB + lt;
    tok_e[n]  = make_int2(le[lt][0], le[lt][1]);
    tok_ls[n] = make_int2(ls[lt][0], ls[lt][1]);
    tok_g[n]  = make_float2(lg[lt][0], lg[lt][1]);
  }
}

__global__ __launch_bounds__(256) void prep_kernel(const float* __restrict__ W1,
    unsigned short* __restrict__ W1t, const float* __restrict__ W2,
    unsigned short* __restrict__ W2t, const float* __restrict__ x,
    const float* __restrict__ Wg, int* __restrict__ hist_part, int2* __restrict__ tok_e,
    int2* __restrict__ tok_ls, float2* __restrict__ tok_g) {
  const int b = blockIdx.x;
  if (b < GB_BLOCKS) {             // gate first: long-latency blocks overlap transposes
    gate_body(b, x, Wg, hist_part, tok_e, tok_ls, tok_g);
  } else if (b < PREP_W2) {        // W1: R=512, C=2048 -> 64 x 16 x 8 tiles
    const int q = b - PREP_W1;
    transpose_tile(W1, W1t, DIM, FDIM, q & 63, (q >> 6) & 15, q >> 10);
  } else {                         // W2: R=2048, C=512 -> 16 x 64 x 8 tiles
    const int q = b - PREP_W2;
    transpose_tile(W2, W2t, FDIM, DIM, q & 15, (q >> 4) & 63, q >> 10);
  }
}

// ---------------- scan: hist_part -> absolute base_part, offsets, mtile_e ----------------
__global__ __launch_bounds__(256) void scan_kernel(const int* __restrict__ hist_part,
    int* __restrict__ offsets, int* __restrict__ base_part, int* __restrict__ mtile_e) {
  __shared__ int hp[GB_BLOCKS * NEXP];   // 16 KB
  __shared__ int segsum[8][NEXP];
  __shared__ int segbase[8][NEXP];
  __shared__ int tot[NEXP];
  __shared__ int soff[NEXP + 1];
  for (int i = threadIdx.x; i < GB_BLOCKS * NEXP; i += 256) hp[i] = hist_part[i];
  __syncthreads();
  if (threadIdx.x < 64) {
    const int e = threadIdx.x & 7, s = threadIdx.x >> 3;   // 8 segments x 8 experts
    int run = 0;
    for (int b = s * 64; b < s * 64 + 64; b++) {
      int v = hp[b * NEXP + e]; hp[b * NEXP + e] = run; run += v;  // exclusive in-segment
    }
    segsum[s][e] = run;
  }
  __syncthreads();
  if (threadIdx.x < NEXP) {
    const int e = threadIdx.x;
    int run = 0;
    for (int s = 0; s < 8; s++) { segbase[s][e] = run; run += segsum[s][e]; }
    tot[e] = run;
  }
  __syncthreads();
  if (threadIdx.x == 0) {
    int off = 0;
    for (int e = 0; e < NEXP; e++) { soff[e] = off; offsets[e] = off; off += (tot[e] + 127) & ~127; }
    soff[NEXP] = off; offsets[NEXP] = off;
    for (int t = 0; t < NMT; t++) {
      int r = t * 128, e = NEXP - 1;
      for (int q = 0; q < NEXP; q++)
        if (r >= soff[q] && r < soff[q + 1]) { e = q; break; }
      mtile_e[t] = e;
    }
  }
  __syncthreads();
  for (int i = threadIdx.x; i < GB_BLOCKS * NEXP; i += 256) {
    const int b = i >> 3, e = i & 7;
    base_part[i] = soff[e] + segbase[b >> 6][e] + hp[i];
  }
}

// ---------------- gather: resolve rows, write xg (both slots), persist rows ----------------
__global__ void gather_kernel(const float* __restrict__ x, const int2* __restrict__ tok_e,
                              const int2* __restrict__ tok_ls, const int* __restrict__ base_part,
                              ushort4* __restrict__ xg, int2* __restrict__ rows) {
  const int n = blockIdx.x;
  int2 te = tok_e[n]; int2 tl = tok_ls[n];
  const int gb = n / GTPB;
  const int r0 = base_part[gb * NEXP + te.x] + tl.x;
  const int r1 = base_part[gb * NEXP + te.y] + tl.y;
  if (threadIdx.x == 0) rows[n] = make_int2(r0, r1);
  const float4* xr = (const float4*)(x + (size_t)n * DIM);
  float4 v = xr[threadIdx.x];
  ushort4 o;
  o.x = f2bf(v.x); o.y = f2bf(v.y); o.z = f2bf(v.z); o.w = f2bf(v.w);
  xg[(size_t)r0 * (DIM / 4) + threadIdx.x] = o;
  xg[(size_t)r1 * (DIM / 4) + threadIdx.x] = o;
}

// ---------------- 128x128xBK64 bf16 MFMA GEMM core, global_load_lds staging ----------------
// BK=64: 8 gld16 + 32 MFMA per barrier pair. XOR chunk swizzle (slot [row][c]
// holds global chunk c^(row&7)); read side 2-way bank aliasing (free).
template <int K, int LDA, int LDB>
__device__ __forceinline__ void gemm_core(const unsigned short* __restrict__ A,
                                          const unsigned short* __restrict__ B,
                                          int m0, int n0, f32x4 acc[4][4]) {
  __shared__ __align__(16) unsigned short As[128 * 64];  // 16 KB
  __shared__ __align__(16) unsigned short Bs[128 * 64];  // 16 KB
  const int tid = threadIdx.x;
  const int wid = tid >> 6, lane = tid & 63;
  const int wm = (wid >> 1) * 64, wn = (wid & 1) * 64;
  const int quad = lane >> 4, l16 = lane & 15;
  const int srow = tid >> 3;                        // 0..31
  const int scol = ((tid & 7) ^ (srow & 7)) << 3;   // swizzled source chunk (elems)
  unsigned short* As_w = As + 512 * wid;            // wave-uniform base (16B*64 per wave)
  unsigned short* Bs_w = Bs + 512 * wid;
  const int r7 = (l16 & 7) << 3;                    // read-side swizzle key (elems)
  const unsigned short* Ar = A + (size_t)(m0 + srow) * LDA + scol;
  const unsigned short* Br = B + (size_t)(n0 + srow) * LDB + scol;
  #pragma unroll 1
  for (int kt = 0; kt < K; kt += 64) {
    __syncthreads();                      // prior iteration's LDS reads done
    #pragma unroll
    for (int p = 0; p < 4; p++) {
      gld16(Ar + (size_t)(32 * p) * LDA + kt, As_w + p * 2048);
      gld16(Br + (size_t)(32 * p) * LDB + kt, Bs_w + p * 2048);
    }
    __syncthreads();                      // drains vmcnt before ds_read
    #pragma unroll
    for (int kk = 0; kk < 2; kk++) {
      const int swz = ((kk * 4 + quad) << 3) ^ r7;  // swizzled chunk offset (elems)
      bf16x8 af[4], bfr[4];
      #pragma unroll
      for (int i = 0; i < 4; i++) {
        af[i]  = *(const bf16x8*)(As + (wm + i * 16 + l16) * 64 + swz);
        bfr[i] = *(const bf16x8*)(Bs + (wn + i * 16 + l16) * 64 + swz);
      }
      #pragma unroll
      for (int mi = 0; mi < 4; mi++)
        #pragma unroll
        for (int ni = 0; ni < 4; ni++)
          acc[mi][ni] = __builtin_amdgcn_mfma_f32_16x16x32_bf16(af[mi], bfr[ni], acc[mi][ni], 0, 0, 0);
    }
  }
}

// ---------------- GEMM1: h = relu(xg @ W1[e] + b1[e]) -> bf16 ----------------
__global__ __launch_bounds__(256, 4) void gemm1_kernel(const unsigned short* __restrict__ xg,
    const unsigned short* __restrict__ W1t, const int* __restrict__ mtile_e,
    const float* __restrict__ b1, unsigned short* __restrict__ h) {
  const int bm = blockIdx.x, bn = blockIdx.y;
  const int e = mtile_e[bm];
  f32x4 acc[4][4];
  #pragma unroll
  for (int i = 0; i < 4; i++)
    #pragma unroll
    for (int j = 0; j < 4; j++) acc[i][j] = (f32x4){0.f, 0.f, 0.f, 0.f};
  gemm_core<DIM, DIM, DIM>(xg, W1t + (size_t)e * FDIM * DIM, bm * 128, bn * 128, acc);
  const int tid = threadIdx.x, wid = tid >> 6, lane = tid & 63;
  const int wm = (wid >> 1) * 64, wn = (wid & 1) * 64, quad = lane >> 4, l16 = lane & 15;
  #pragma unroll
  for (int mi = 0; mi < 4; mi++) {
    #pragma unroll
    for (int ni = 0; ni < 4; ni++) {
      const int col = bn * 128 + wn + ni * 16 + l16;
      const float bb = b1[e * FDIM + col];
      #pragma unroll
      for (int r = 0; r < 4; r++) {
        const int row = bm * 128 + wm + mi * 16 + quad * 4 + r;
        float v = acc[mi][ni][r] + bb;
        h[(size_t)row * FDIM + col] = f2bf(v > 0.f ? v : 0.f);
      }
    }
  }
}

// ---------------- GEMM2 (split-K, deterministic): ks=0 -> o0 fp32, ks=1 -> o1 bf16 ----------------
__global__ __launch_bounds__(256, 4) void gemm2_kernel(const unsigned short* __restrict__ h,
    const unsigned short* __restrict__ W2t, const int* __restrict__ mtile_e,
    float* __restrict__ o0, unsigned short* __restrict__ o1) {
  const int bm = blockIdx.x, bn = blockIdx.y, ks = blockIdx.z;
  const int e = mtile_e[bm];
  const int k0 = ks * (FDIM / KSPLIT);
  f32x4 acc[4][4];
  #pragma unroll
  for (int i = 0; i < 4; i++)
    #pragma unroll
    for (int j = 0; j < 4; j++) acc[i][j] = (f32x4){0.f, 0.f, 0.f, 0.f};
  gemm_core<FDIM / KSPLIT, FDIM, FDIM>(h + k0, W2t + (size_t)e * DIM * FDIM + k0,
                                       bm * 128, bn * 128, acc);
  const int tid = threadIdx.x, wid = tid >> 6, lane = tid & 63;
  const int wm = (wid >> 1) * 64, wn = (wid & 1) * 64, quad = lane >> 4, l16 = lane & 15;
  if (ks == 0) {
    #pragma unroll
    for (int mi = 0; mi < 4; mi++)
      #pragma unroll
      for (int r = 0; r < 4; r++) {
        const int row = bm * 128 + wm + mi * 16 + quad * 4 + r;
        #pragma unroll
        for (int ni = 0; ni < 4; ni++) {
          const int col = bn * 128 + wn + ni * 16 + l16;
          o0[(size_t)row * DIM + col] = acc[mi][ni][r];
        }
      }
  } else {
    #pragma unroll
    for (int mi = 0; mi < 4; mi++)
      #pragma unroll
      for (int r = 0; r < 4; r++) {
        const int row = bm * 128 + wm + mi * 16 + quad * 4 + r;
        #pragma unroll
        for (int ni = 0; ni < 4; ni++) {
          const int col = bn * 128 + wn + ni * 16 + l16;
          o1[(size_t)row * DIM + col] = f2bf(acc[mi][ni][r]);
        }
      }
  }
}

// ---------------- combine: out[n] = log(g0*exp(o(r0)+b2[e0]) + g1*exp(o(r1)+b2[e1])) ----------------
__global__ void combine_kernel(const float* __restrict__ o0, const unsigned short* __restrict__ o1,
                               const int2* __restrict__ tok_e, const int2* __restrict__ rows,
                               const float2* __restrict__ tok_g, const float* __restrict__ b2,
                               float* __restrict__ out) {
  const int n = blockIdx.x;
  const int c = threadIdx.x * 4;  // 128 threads x float4
  int2 te = tok_e[n]; int2 rr = rows[n]; float2 tg = tok_g[n];
  const int r0 = rr.x, r1 = rr.y;
  float4 a0 = *(const float4*)(o0 + (size_t)r0 * DIM + c);
  float4 a1 = *(const float4*)(o0 + (size_t)r1 * DIM + c);
  ushort4 p0 = *(const ushort4*)(o1 + (size_t)r0 * DIM + c);
  ushort4 p1 = *(const ushort4*)(o1 + (size_t)r1 * DIM + c);
  float4 c0 = *(const float4*)(b2 + te.x * DIM + c);
  float4 c1 = *(const float4*)(b2 + te.y * DIM + c);
  float4 res;
  #pragma unroll
  for (int j = 0; j < 4; j++) {
    float v0 = ((const float*)&a0)[j] + bf2f(((const unsigned short*)&p0)[j]) + ((const float*)&c0)[j];
    float v1 = ((const float*)&a1)[j] + bf2f(((const unsigned short*)&p1)[j]) + ((const float*)&c1)[j];
    float v = tg.x * expf(v0) + tg.y * expf(v1);
    v = (v == 0.0f) ? 2.220446049250313e-16f : v;
    ((float*)&res)[j] = logf(v);
  }
  *(float4*)(out + (size_t)n * DIM + c) = res;
}

extern "C" void kernel_launch(void* const* d_in, const int* in_sizes, int n_in,
                              void* d_out, int out_size, void* d_ws, size_t ws_size,
                              hipStream_t stream) {
  const float* x  = (const float*)d_in[0];
  const float* Wg = (const float*)d_in[1];
  const float* W1 = (const float*)d_in[2];
  const float* b1 = (const float*)d_in[3];
  const float* W2 = (const float*)d_in[4];
  const float* b2 = (const float*)d_in[5];
  float* out = (float*)d_out;
  char* ws = (char*)d_ws;

  unsigned short* W1t = (unsigned short*)(ws + OFF_W1T);
  unsigned short* W2t = (unsigned short*)(ws + OFF_W2T);
  unsigned short* h   = (unsigned short*)(ws + OFF_H);
  int* meta    = (int*)(ws + OFF_META);
  int* offsets = meta;           // [9]
  int* mtile_e = meta + 16;      // [136]
  unsigned short* xg = (unsigned short*)(ws + OFF_XG);
  unsigned short* o1 = (unsigned short*)(ws + OFF_O1);  // aliases xg (dead after gemm1)
  float* o0      = (float*)(ws + OFF_O0);
  int2* tok_e    = (int2*)(ws + OFF_TOKE);
  int2* tok_ls   = (int2*)(ws + OFF_TOKLS);
  float2* tok_g  = (float2*)(ws + OFF_TOKG);
  int* hist_part = (int*)(ws + OFF_HISTP);
  int* base_part = (int*)(ws + OFF_BASEP);
  int2* rows     = (int2*)(ws + OFF_ROWS);

  prep_kernel<<<GB_BLOCKS + 2 * 8192, 256, 0, stream>>>(W1, W1t, W2, W2t, x, Wg,
                                                        hist_part, tok_e, tok_ls, tok_g);
  scan_kernel<<<1, 256, 0, stream>>>(hist_part, offsets, base_part, mtile_e);
  gather_kernel<<<NTOK, 128, 0, stream>>>(x, tok_e, tok_ls, base_part, (ushort4*)xg, rows);
  gemm1_kernel<<<dim3(NMT, FDIM / 128), 256, 0, stream>>>(xg, W1t, mtile_e, b1, h);
  gemm2_kernel<<<dim3(NMT, DIM / 128, KSPLIT), 256, 0, stream>>>(h, W2t, mtile_e, o0, o1);
  combine_kernel<<<NTOK, 128, 0, stream>>>(o0, o1, tok_e, rows, tok_g, b2, out);
}